// Round 1
// baseline (1444.944 us; speedup 1.0000x reference)
//
#include <hip/hip_runtime.h>
#include <stdint.h>

// DCGRU cell on MI355X.
// Pipeline:
//  1. cast supports -> Abf (bf16, [A0;A1] stacked 4096x2048)
//  2. build X = concat(inputs,hx) bf16 (4224x2048); copy input rows into X'
//  3. GEMM1: Y1 = X @ [A0^T | A1^T]              (bf16 MFMA, 4224x4096)
//  4. GEMM2: Y2 = 2*(Y1_g @ Ag^T) - X  (fused Chebyshev epilogue)
//  5. proj_ru: value = sigmoid(h @ W_ru + b_ru); X'[2:66] = r*hx ; Ubuf = u
//  6. GEMM1': Y1 = X' @ [A0^T | A1^T]
//  7. GEMM2': Y2 = 2*(Y1_g @ Ag^T) - X'
//  8. proj_cf: C = tanh(h' @ W_c + b_c); out = u*hx + (1-u)*C

typedef unsigned short ushort_t;
typedef __attribute__((ext_vector_type(8))) __bf16 bf16x8;
typedef __attribute__((ext_vector_type(4))) float f32x4;

__device__ __forceinline__ ushort_t f2bf(float f) {
  union { float f; uint32_t u; } v; v.f = f;
  uint32_t r = v.u + 0x7FFFu + ((v.u >> 16) & 1u);   // RNE
  return (ushort_t)(r >> 16);
}
__device__ __forceinline__ float bf2f(ushort_t u) {
  union { uint32_t u; float f; } v; v.u = ((uint32_t)u) << 16;
  return v.f;
}

__device__ __forceinline__ void gl_lds16(const void* g, void* l) {
  __builtin_amdgcn_global_load_lds(
      (const __attribute__((address_space(1))) void*)g,
      (__attribute__((address_space(3))) void*)l, 16, 0, 0);
}

// ---------------- prep kernels ----------------

__global__ void k_cast(const float* __restrict__ src, ushort_t* __restrict__ dst, int n) {
  for (int i = (blockIdx.x * 256 + threadIdx.x) * 4; i < n; i += gridDim.x * 256 * 4) {
    float4 v = *(const float4*)(src + i);
    ushort4 r;
    r.x = f2bf(v.x); r.y = f2bf(v.y); r.z = f2bf(v.z); r.w = f2bf(v.w);
    *(ushort4*)(dst + i) = r;
  }
}

// one block per row r = b*66+c of X (4224 rows); also fills X' rows c<2
__global__ void k_build_X(const float* __restrict__ inputs, const float* __restrict__ hx,
                          ushort_t* __restrict__ Xbf, ushort_t* __restrict__ Xpbf) {
  int r = blockIdx.x;
  int b = r / 66, c = r - b * 66;
  const float* src = (c < 2) ? (inputs + ((size_t)b * 2 + c) * 2048)
                             : (hx + ((size_t)b * 64 + (c - 2)) * 2048);
  ushort_t* d1 = Xbf + (size_t)r * 2048;
  ushort_t* d2 = (c < 2) ? (Xpbf + (size_t)r * 2048) : nullptr;
  for (int n = threadIdx.x * 4; n < 2048; n += 256 * 4) {
    float4 v = *(const float4*)(src + n);
    ushort4 rr;
    rr.x = f2bf(v.x); rr.y = f2bf(v.y); rr.z = f2bf(v.z); rr.w = f2bf(v.w);
    *(ushort4*)(d1 + n) = rr;
    if (d2) *(ushort4*)(d2 + n) = rr;
  }
}

// ---------------- bf16 MFMA GEMM (NT, m97-style 128x128 tile) ----------------
// C[r,m] = sum_k A[r,k]*B[m,k].  B rows = Abf stacked (row m in [0,4096)).
// EPI==1: A-operand column-group offset (+= g*2048) and out = 2*acc - Xres[r, m&2047].
template <int EPI>
__global__ __launch_bounds__(256, 2) void gemm_bt(
    const ushort_t* __restrict__ Aop, int lda,
    const ushort_t* __restrict__ Bop,
    const ushort_t* __restrict__ Xres,
    ushort_t* __restrict__ Cout, int ldc) {
  __shared__ ushort_t As[128 * 32];
  __shared__ ushort_t Bs[128 * 32];
  const int tid = threadIdx.x;
  const int l = tid & 63, w = tid >> 6;
  const int wr = w >> 1, wc = w & 1;
  const int lr = l & 15, lk = l >> 4;
  const int r0 = blockIdx.x * 128;
  const int m0 = blockIdx.y * 128;
  if (EPI == 1) Aop += (size_t)(blockIdx.y >> 4) * 2048;

  f32x4 acc[4][4];
  const f32x4 zero = {0.f, 0.f, 0.f, 0.f};
#pragma unroll
  for (int mi = 0; mi < 4; mi++)
#pragma unroll
    for (int ni = 0; ni < 4; ni++) acc[mi][ni] = zero;

  const int rowA = l >> 2;          // row within 16-row chunk
  const int kcol = (l & 3) * 8;     // bf16 elements along k

  for (int kk = 0; kk < 64; ++kk) {
    const int k0 = kk * 32;
    const int c0 = 2 * w, c1 = 2 * w + 1;
    gl_lds16(Aop + (size_t)(r0 + c0 * 16 + rowA) * lda + k0 + kcol, (void*)&As[c0 * 512]);
    gl_lds16(Aop + (size_t)(r0 + c1 * 16 + rowA) * lda + k0 + kcol, (void*)&As[c1 * 512]);
    gl_lds16(Bop + (size_t)(m0 + c0 * 16 + rowA) * 2048 + k0 + kcol, (void*)&Bs[c0 * 512]);
    gl_lds16(Bop + (size_t)(m0 + c1 * 16 + rowA) * 2048 + k0 + kcol, (void*)&Bs[c1 * 512]);
    __syncthreads();

    bf16x8 af[4], bfv[4];
#pragma unroll
    for (int i = 0; i < 4; i++)
      af[i] = *(const bf16x8*)&As[(wr * 64 + i * 16 + lr) * 32 + lk * 8];
#pragma unroll
    for (int i = 0; i < 4; i++)
      bfv[i] = *(const bf16x8*)&Bs[(wc * 64 + i * 16 + lr) * 32 + lk * 8];
#pragma unroll
    for (int mi = 0; mi < 4; mi++)
#pragma unroll
      for (int ni = 0; ni < 4; ni++)
        acc[mi][ni] = __builtin_amdgcn_mfma_f32_16x16x32_bf16(af[mi], bfv[ni], acc[mi][ni], 0, 0, 0);
    __syncthreads();
  }

#pragma unroll
  for (int mi = 0; mi < 4; mi++) {
#pragma unroll
    for (int ni = 0; ni < 4; ni++) {
      const int row0 = r0 + wr * 64 + mi * 16 + lk * 4;
      const int col = m0 + wc * 64 + ni * 16 + lr;
#pragma unroll
      for (int j = 0; j < 4; j++) {
        float v = acc[mi][ni][j];
        if (EPI == 1) v = 2.f * v - bf2f(Xres[(size_t)(row0 + j) * 2048 + (col & 2047)]);
        Cout[(size_t)(row0 + j) * ldc + col] = f2bf(v);
      }
    }
  }
}

// ---------------- projection kernels (vector f32) ----------------
// h[K=(k,c)] feats: k0=X, k1=Y1[:, :2048], k2=Y2[:, :2048], k3=Y1[:, 2048:], k4=Y2[:, 2048:]

__global__ __launch_bounds__(256) void proj_ru(
    const ushort_t* __restrict__ Xbf, const ushort_t* __restrict__ Y1,
    const ushort_t* __restrict__ Y2, const float* __restrict__ W,
    const float* __restrict__ bias, const float* __restrict__ hx,
    ushort_t* __restrict__ Xpbf, float* __restrict__ Ubuf) {
  __shared__ ushort_t h[330 * 32];
  const int tid = threadIdx.x;
  const int b = blockIdx.y;
  const int n0 = blockIdx.x * 32;
  for (int idx = tid; idx < 330 * 32; idx += 256) {
    int K = idx >> 5, nn = idx & 31;
    int k = K / 66, c = K - k * 66;
    size_t rc = (size_t)b * 66 + c;
    const ushort_t* ptr;
    switch (k) {
      case 0:  ptr = Xbf + rc * 2048 + n0 + nn; break;
      case 1:  ptr = Y1 + rc * 4096 + n0 + nn; break;
      case 2:  ptr = Y2 + rc * 4096 + n0 + nn; break;
      case 3:  ptr = Y1 + rc * 4096 + 2048 + n0 + nn; break;
      default: ptr = Y2 + rc * 4096 + 2048 + n0 + nn; break;
    }
    h[idx] = *ptr;
  }
  __syncthreads();
  const int nn = tid & 31, og = tid >> 5, o0 = og * 16;
  float acc[16];
#pragma unroll
  for (int j = 0; j < 16; j++) acc[j] = 0.f;
#pragma unroll 2
  for (int K = 0; K < 330; ++K) {
    float hv = bf2f(h[K * 32 + nn]);
    const float4* wp = (const float4*)(W + (size_t)K * 128 + o0);
    float4 w0 = wp[0], w1 = wp[1], w2 = wp[2], w3 = wp[3];
    acc[0] += hv * w0.x; acc[1] += hv * w0.y; acc[2] += hv * w0.z; acc[3] += hv * w0.w;
    acc[4] += hv * w1.x; acc[5] += hv * w1.y; acc[6] += hv * w1.z; acc[7] += hv * w1.w;
    acc[8] += hv * w2.x; acc[9] += hv * w2.y; acc[10] += hv * w2.z; acc[11] += hv * w2.w;
    acc[12] += hv * w3.x; acc[13] += hv * w3.y; acc[14] += hv * w3.z; acc[15] += hv * w3.w;
  }
  const int n = n0 + nn;
#pragma unroll
  for (int j = 0; j < 16; j++) {
    int o = o0 + j;
    float v = acc[j] + bias[o];
    float s = 1.f / (1.f + expf(-v));
    if (o < 64) {  // r-part: build X' rows 2..65 = r*hx
      float hxv = hx[((size_t)b * 64 + o) * 2048 + n];
      Xpbf[((size_t)b * 66 + 2 + o) * 2048 + n] = f2bf(s * hxv);
    } else {       // u-part
      Ubuf[((size_t)b * 64 + (o - 64)) * 2048 + n] = s;
    }
  }
}

__global__ __launch_bounds__(256) void proj_cf(
    const ushort_t* __restrict__ Xpbf, const ushort_t* __restrict__ Y1,
    const ushort_t* __restrict__ Y2, const float* __restrict__ W,
    const float* __restrict__ bias, const float* __restrict__ hx,
    const float* __restrict__ Ubuf, float* __restrict__ out) {
  __shared__ ushort_t h[330 * 64];
  const int tid = threadIdx.x;
  const int b = blockIdx.y;
  const int n0 = blockIdx.x * 64;
  for (int idx = tid; idx < 330 * 64; idx += 256) {
    int K = idx >> 6, nn = idx & 63;
    int k = K / 66, c = K - k * 66;
    size_t rc = (size_t)b * 66 + c;
    const ushort_t* ptr;
    switch (k) {
      case 0:  ptr = Xpbf + rc * 2048 + n0 + nn; break;
      case 1:  ptr = Y1 + rc * 4096 + n0 + nn; break;
      case 2:  ptr = Y2 + rc * 4096 + n0 + nn; break;
      case 3:  ptr = Y1 + rc * 4096 + 2048 + n0 + nn; break;
      default: ptr = Y2 + rc * 4096 + 2048 + n0 + nn; break;
    }
    h[idx] = *ptr;
  }
  __syncthreads();
  const int nn = tid & 63, og = tid >> 6, o0 = og * 16;
  float acc[16];
#pragma unroll
  for (int j = 0; j < 16; j++) acc[j] = 0.f;
#pragma unroll 2
  for (int K = 0; K < 330; ++K) {
    float hv = bf2f(h[K * 64 + nn]);
    const float4* wp = (const float4*)(W + (size_t)K * 64 + o0);
    float4 w0 = wp[0], w1 = wp[1], w2 = wp[2], w3 = wp[3];
    acc[0] += hv * w0.x; acc[1] += hv * w0.y; acc[2] += hv * w0.z; acc[3] += hv * w0.w;
    acc[4] += hv * w1.x; acc[5] += hv * w1.y; acc[6] += hv * w1.z; acc[7] += hv * w1.w;
    acc[8] += hv * w2.x; acc[9] += hv * w2.y; acc[10] += hv * w2.z; acc[11] += hv * w2.w;
    acc[12] += hv * w3.x; acc[13] += hv * w3.y; acc[14] += hv * w3.z; acc[15] += hv * w3.w;
  }
  const int n = n0 + nn;
#pragma unroll
  for (int j = 0; j < 16; j++) {
    int o = o0 + j;
    float v = acc[j] + bias[o];
    float Cv = tanhf(v);
    size_t oi = ((size_t)b * 64 + o) * 2048 + n;
    float u = Ubuf[oi];
    out[oi] = u * hx[oi] + (1.f - u) * Cv;
  }
}

// ---------------- launcher ----------------

extern "C" void kernel_launch(void* const* d_in, const int* in_sizes, int n_in,
                              void* d_out, int out_size, void* d_ws, size_t ws_size,
                              hipStream_t stream) {
  (void)in_sizes; (void)n_in; (void)out_size; (void)ws_size;
  const float* inputs = (const float*)d_in[0];
  const float* hx     = (const float*)d_in[1];
  const float* s0     = (const float*)d_in[2];
  const float* s1     = (const float*)d_in[3];
  const float* W_ru   = (const float*)d_in[4];
  const float* b_ru   = (const float*)d_in[5];
  const float* W_c    = (const float*)d_in[6];
  const float* b_c    = (const float*)d_in[7];
  float* out = (float*)d_out;

  char* p = (char*)d_ws;
  ushort_t* Abf  = (ushort_t*)p; p += (size_t)4096 * 2048 * 2;   // 16.78 MB
  ushort_t* Xbf  = (ushort_t*)p; p += (size_t)4224 * 2048 * 2;   // 17.30 MB
  ushort_t* Xpbf = (ushort_t*)p; p += (size_t)4224 * 2048 * 2;   // 17.30 MB
  ushort_t* Y1   = (ushort_t*)p; p += (size_t)4224 * 4096 * 2;   // 34.60 MB
  ushort_t* Y2   = (ushort_t*)p; p += (size_t)4224 * 4096 * 2;   // 34.60 MB
  float*    Ubuf = (float*)p;    p += (size_t)64 * 64 * 2048 * 4;// 33.55 MB

  k_cast<<<1024, 256, 0, stream>>>(s0, Abf, 4194304);
  k_cast<<<1024, 256, 0, stream>>>(s1, Abf + 4194304, 4194304);
  k_build_X<<<4224, 256, 0, stream>>>(inputs, hx, Xbf, Xpbf);

  dim3 g(33, 32);
  // conv1
  gemm_bt<0><<<g, 256, 0, stream>>>(Xbf, 2048, Abf, nullptr, Y1, 4096);
  gemm_bt<1><<<g, 256, 0, stream>>>(Y1, 4096, Abf, Xbf, Y2, 4096);
  proj_ru<<<dim3(64, 64), 256, 0, stream>>>(Xbf, Y1, Y2, W_ru, b_ru, hx, Xpbf, Ubuf);
  // conv2
  gemm_bt<0><<<g, 256, 0, stream>>>(Xpbf, 2048, Abf, nullptr, Y1, 4096);
  gemm_bt<1><<<g, 256, 0, stream>>>(Y1, 4096, Abf, Xpbf, Y2, 4096);
  proj_cf<<<dim3(32, 64), 256, 0, stream>>>(Xpbf, Y1, Y2, W_c, b_c, hx, Ubuf, out);
}

// Round 2
// 641.639 us; speedup vs baseline: 2.2520x; 2.2520x over previous
//
#include <hip/hip_runtime.h>
#include <stdint.h>

// DCGRU cell on MI355X — round 2: MFMA projections via packed-transposed Ht.
//
// Buffers (d_ws, ~178 MB):
//   Abf  [4096][2048] bf16  supports stacked [A0;A1]
//   Xbf  [4224][2048] bf16  X rows (b*66+c); rows 2..65 overwritten with r*hx by proj_ru
//   Y1   [4224][4096] bf16  x1 (both supports) — operand for GEMM2
//   Ht   [131072][352] bf16 packed H^T: row m=(b*2048+n), col K = slot*66+c
//                           slots: 0=x, 1=A0x1, 2=A0x2, 3=A1x1, 4=A1x2; cols 330..351 pad
//   Ubuf [64*64*2048] bf16  u gate
//   Wt_ru/Wt_c [128][352] bf16  W^T zero-padded
//
// Pipeline per conv: trans_slot0 -> GEMM1 (Y1 + Ht slots 1,3) -> GEMM2 (Chebyshev,
// Ht slots 2,4) -> proj (MFMA, fused gate epilogue).

typedef unsigned short ushort_t;
typedef __attribute__((ext_vector_type(8))) __bf16 bf16x8;
typedef __attribute__((ext_vector_type(4))) float f32x4;

#define KP 352            // padded K for projections
#define MROWS 131072      // 64 b * 2048 n

__device__ __forceinline__ ushort_t f2bf(float f) {
  union { float f; uint32_t u; } v; v.f = f;
  uint32_t r = v.u + 0x7FFFu + ((v.u >> 16) & 1u);   // RNE
  return (ushort_t)(r >> 16);
}
__device__ __forceinline__ float bf2f(ushort_t u) {
  union { uint32_t u; float f; } v; v.u = ((uint32_t)u) << 16;
  return v.f;
}

__device__ __forceinline__ void gl_lds16(const void* g, void* l) {
  __builtin_amdgcn_global_load_lds(
      (const __attribute__((address_space(1))) void*)g,
      (__attribute__((address_space(3))) void*)l, 16, 0, 0);
}

// ---------------- prep kernels ----------------

__global__ void k_cast(const float* __restrict__ src, ushort_t* __restrict__ dst, int n) {
  for (int i = (blockIdx.x * 256 + threadIdx.x) * 4; i < n; i += gridDim.x * 256 * 4) {
    float4 v = *(const float4*)(src + i);
    ushort4 r;
    r.x = f2bf(v.x); r.y = f2bf(v.y); r.z = f2bf(v.z); r.w = f2bf(v.w);
    *(ushort4*)(dst + i) = r;
  }
}

// one block per row r = b*66+c of X (4224 rows)
__global__ void k_build_X(const float* __restrict__ inputs, const float* __restrict__ hx,
                          ushort_t* __restrict__ Xbf) {
  int r = blockIdx.x;
  int b = r / 66, c = r - b * 66;
  const float* src = (c < 2) ? (inputs + ((size_t)b * 2 + c) * 2048)
                             : (hx + ((size_t)b * 64 + (c - 2)) * 2048);
  ushort_t* d1 = Xbf + (size_t)r * 2048;
  for (int n = threadIdx.x * 4; n < 2048; n += 256 * 4) {
    float4 v = *(const float4*)(src + n);
    ushort4 rr;
    rr.x = f2bf(v.x); rr.y = f2bf(v.y); rr.z = f2bf(v.z); rr.w = f2bf(v.w);
    *(ushort4*)(d1 + n) = rr;
  }
}

// Wt[o][k] = W[k][o] (bf16), zero-padded to 128 x 352
__global__ void k_pack_W(const float* __restrict__ W, int O, ushort_t* __restrict__ Wt) {
  int o = blockIdx.x;
  for (int k = threadIdx.x; k < KP; k += 256) {
    float v = (k < 330 && o < O) ? W[(size_t)k * O + o] : 0.f;
    Wt[(size_t)o * KP + k] = f2bf(v);
  }
}

// Ht[(b*2048+n)][0..66) = Xbf[(b*66+c)][n] transposed. grid (16, 64)
__global__ __launch_bounds__(256) void k_trans_slot0(const ushort_t* __restrict__ Xbf,
                                                     ushort_t* __restrict__ Ht) {
  __shared__ ushort_t t[66 * 136];
  const int tid = threadIdx.x;
  const int b = blockIdx.y;
  const int n0 = blockIdx.x * 128;
  for (int idx = tid; idx < 66 * 16; idx += 256) {
    int c = idx >> 4, seg = idx & 15;
    bf16x8 v = *(const bf16x8*)&Xbf[((size_t)b * 66 + c) * 2048 + n0 + seg * 8];
    *(bf16x8*)&t[c * 136 + seg * 8] = v;
  }
  __syncthreads();
  for (int idx = tid; idx < 128 * 66; idx += 256) {
    int nn = idx / 66, c = idx - nn * 66;
    Ht[((size_t)b * 2048 + n0 + nn) * KP + c] = t[c * 136 + nn];
  }
}

// ---------------- bf16 MFMA diffusion GEMM (NT, 128x128 tile) ----------------
// MODE 0: C = A@B^T; writes Y1out[r][m] and Ht slot (1+2g).
// MODE 1: C = 2*(A@B^T) - Xres; A offset by g*2048; writes Ht slot (2+2g) only.
template <int MODE>
__global__ __launch_bounds__(256, 2) void gemm_bt(
    const ushort_t* __restrict__ Aop, int lda,
    const ushort_t* __restrict__ Bop,
    const ushort_t* __restrict__ Xres,
    ushort_t* __restrict__ Y1out,
    ushort_t* __restrict__ Ht) {
  __shared__ ushort_t smem[128 * 130];   // As[0..4096) Bs[4096..8192); epilogue: cTile
  ushort_t* As = smem;
  ushort_t* Bs = smem + 4096;
  const int tid = threadIdx.x;
  const int l = tid & 63, w = tid >> 6;
  const int wr = w >> 1, wc = w & 1;
  const int lr = l & 15, lk = l >> 4;
  const int r0 = blockIdx.x * 128;
  const int m0 = blockIdx.y * 128;
  const int g = m0 >> 11;
  if (MODE == 1) Aop += (size_t)g * 2048;

  f32x4 acc[4][4];
  const f32x4 zero = {0.f, 0.f, 0.f, 0.f};
#pragma unroll
  for (int mi = 0; mi < 4; mi++)
#pragma unroll
    for (int ni = 0; ni < 4; ni++) acc[mi][ni] = zero;

  const int rowA = l >> 2;
  const int kcol = (l & 3) * 8;

  for (int kk = 0; kk < 64; ++kk) {
    const int k0 = kk * 32;
    const int c0 = 2 * w, c1 = 2 * w + 1;
    gl_lds16(Aop + (size_t)(r0 + c0 * 16 + rowA) * lda + k0 + kcol, (void*)&As[c0 * 512]);
    gl_lds16(Aop + (size_t)(r0 + c1 * 16 + rowA) * lda + k0 + kcol, (void*)&As[c1 * 512]);
    gl_lds16(Bop + (size_t)(m0 + c0 * 16 + rowA) * 2048 + k0 + kcol, (void*)&Bs[c0 * 512]);
    gl_lds16(Bop + (size_t)(m0 + c1 * 16 + rowA) * 2048 + k0 + kcol, (void*)&Bs[c1 * 512]);
    __syncthreads();

    bf16x8 af[4], bfv[4];
#pragma unroll
    for (int i = 0; i < 4; i++)
      af[i] = *(const bf16x8*)&As[(wr * 64 + i * 16 + lr) * 32 + lk * 8];
#pragma unroll
    for (int i = 0; i < 4; i++)
      bfv[i] = *(const bf16x8*)&Bs[(wc * 64 + i * 16 + lr) * 32 + lk * 8];
#pragma unroll
    for (int mi = 0; mi < 4; mi++)
#pragma unroll
      for (int ni = 0; ni < 4; ni++)
        acc[mi][ni] = __builtin_amdgcn_mfma_f32_16x16x32_bf16(af[mi], bfv[ni], acc[mi][ni], 0, 0, 0);
    __syncthreads();
  }

  // epilogue: optional Y1 direct store + bf16 value into transposed LDS tile
#pragma unroll
  for (int mi = 0; mi < 4; mi++) {
#pragma unroll
    for (int ni = 0; ni < 4; ni++) {
      const int rl0 = wr * 64 + mi * 16 + lk * 4;
      const int cl = wc * 64 + ni * 16 + lr;
      const int col = m0 + cl;
#pragma unroll
      for (int j = 0; j < 4; j++) {
        float v = acc[mi][ni][j];
        if (MODE == 1)
          v = 2.f * v - bf2f(Xres[(size_t)(r0 + rl0 + j) * 2048 + (col & 2047)]);
        ushort_t bv = f2bf(v);
        if (MODE == 0) Y1out[(size_t)(r0 + rl0 + j) * 4096 + col] = bv;
        smem[cl * 130 + rl0 + j] = bv;
      }
    }
  }
  __syncthreads();

  // transposed write into Ht: row m=(b*2048+n), col = slot*66 + c
  const int slotBase = (MODE == 0 ? 1 : 2) + 2 * g;
  const int n_base = m0 & 2047;
#pragma unroll 4
  for (int j2 = 0; j2 < 64; ++j2) {
    int idx = j2 * 256 + tid;
    int mc = idx >> 7, rl = idx & 127;
    unsigned rg = (unsigned)(r0 + rl);
    unsigned b = rg / 66u;
    unsigned c = rg - b * 66u;
    int n = n_base + mc;
    Ht[((size_t)b * 2048 + n) * KP + slotBase * 66 + c] = smem[mc * 130 + rl];
  }
}

// ---------------- MFMA projection GEMM ----------------
// C[m=(b,n)][o] = sum_K Ht[m][K] * Wt[o][K].  M-tile 128 (one b), O-tile 128.
// MODE 0 (RU): s = sigmoid(C + b_ru); o<64 -> Xbf[b*66+2+o][n] = bf16(s*hx);
//              o>=64 -> Ubuf = bf16(s).
// MODE 1 (CF): Cc = tanh(C + b_c) (o<64); out = u*hx + (1-u)*Cc.
template <int MODE>
__global__ __launch_bounds__(256, 2) void proj_mfma(
    const ushort_t* __restrict__ Ht, const ushort_t* __restrict__ Wt,
    const float* __restrict__ bias, const float* __restrict__ hx,
    ushort_t* __restrict__ Xbf, ushort_t* __restrict__ Ubuf,
    float* __restrict__ out) {
  __shared__ ushort_t smem[128 * 130];
  ushort_t* As = smem;
  ushort_t* Bs = smem + 4096;
  const int tid = threadIdx.x;
  const int l = tid & 63, w = tid >> 6;
  const int wr = w >> 1, wc = w & 1;
  const int lr = l & 15, lk = l >> 4;
  const int bb = blockIdx.x >> 4;
  const int n0 = (blockIdx.x & 15) * 128;
  const size_t m0 = (size_t)bb * 2048 + n0;

  f32x4 acc[4][4];
  const f32x4 zero = {0.f, 0.f, 0.f, 0.f};
#pragma unroll
  for (int mi = 0; mi < 4; mi++)
#pragma unroll
    for (int ni = 0; ni < 4; ni++) acc[mi][ni] = zero;

  const int rowA = l >> 2;
  const int kcol = (l & 3) * 8;

  for (int kk = 0; kk < 11; ++kk) {
    const int k0 = kk * 32;
    const int c0 = 2 * w, c1 = 2 * w + 1;
    gl_lds16(Ht + (m0 + c0 * 16 + rowA) * KP + k0 + kcol, (void*)&As[c0 * 512]);
    gl_lds16(Ht + (m0 + c1 * 16 + rowA) * KP + k0 + kcol, (void*)&As[c1 * 512]);
    gl_lds16(Wt + (size_t)(c0 * 16 + rowA) * KP + k0 + kcol, (void*)&Bs[c0 * 512]);
    gl_lds16(Wt + (size_t)(c1 * 16 + rowA) * KP + k0 + kcol, (void*)&Bs[c1 * 512]);
    __syncthreads();

    bf16x8 af[4], bfv[4];
#pragma unroll
    for (int i = 0; i < 4; i++)
      af[i] = *(const bf16x8*)&As[(wr * 64 + i * 16 + lr) * 32 + lk * 8];
#pragma unroll
    for (int i = 0; i < 4; i++)
      bfv[i] = *(const bf16x8*)&Bs[(wc * 64 + i * 16 + lr) * 32 + lk * 8];
#pragma unroll
    for (int mi = 0; mi < 4; mi++)
#pragma unroll
      for (int ni = 0; ni < 4; ni++)
        acc[mi][ni] = __builtin_amdgcn_mfma_f32_16x16x32_bf16(af[mi], bfv[ni], acc[mi][ni], 0, 0, 0);
    __syncthreads();
  }

  // activation into transposed LDS tile sTile[o][m]
#pragma unroll
  for (int mi = 0; mi < 4; mi++) {
#pragma unroll
    for (int ni = 0; ni < 4; ni++) {
      const int rl0 = wr * 64 + mi * 16 + lk * 4;
      const int o = wc * 64 + ni * 16 + lr;
      float bv = (MODE == 0 || o < 64) ? bias[o] : 0.f;
#pragma unroll
      for (int j = 0; j < 4; j++) {
        float v = acc[mi][ni][j] + bv;
        float s;
        if (MODE == 0) s = 1.f / (1.f + expf(-v));
        else           s = tanhf(v);
        smem[o * 130 + rl0 + j] = f2bf(s);
      }
    }
  }
  __syncthreads();

  if (MODE == 0) {
#pragma unroll 4
    for (int j2 = 0; j2 < 64; ++j2) {
      int idx = j2 * 256 + tid;
      int o = idx >> 7, m = idx & 127;
      ushort_t sv = smem[o * 130 + m];
      int n = n0 + m;
      if (o < 64) {
        float s = bf2f(sv);
        float hxv = hx[((size_t)bb * 64 + o) * 2048 + n];
        Xbf[((size_t)bb * 66 + 2 + o) * 2048 + n] = f2bf(s * hxv);
      } else {
        Ubuf[((size_t)bb * 64 + (o - 64)) * 2048 + n] = sv;
      }
    }
  } else {
#pragma unroll 4
    for (int j2 = 0; j2 < 32; ++j2) {
      int idx = j2 * 256 + tid;
      int o = idx >> 7, m = idx & 127;
      float Cv = bf2f(smem[o * 130 + m]);
      int n = n0 + m;
      size_t oi = ((size_t)bb * 64 + o) * 2048 + n;
      float u = bf2f(Ubuf[oi]);
      out[oi] = u * hx[oi] + (1.f - u) * Cv;
    }
  }
}

// ---------------- launcher ----------------

extern "C" void kernel_launch(void* const* d_in, const int* in_sizes, int n_in,
                              void* d_out, int out_size, void* d_ws, size_t ws_size,
                              hipStream_t stream) {
  (void)in_sizes; (void)n_in; (void)out_size; (void)ws_size;
  const float* inputs = (const float*)d_in[0];
  const float* hx     = (const float*)d_in[1];
  const float* s0     = (const float*)d_in[2];
  const float* s1     = (const float*)d_in[3];
  const float* W_ru   = (const float*)d_in[4];
  const float* b_ru   = (const float*)d_in[5];
  const float* W_c    = (const float*)d_in[6];
  const float* b_c    = (const float*)d_in[7];
  float* out = (float*)d_out;

  char* p = (char*)d_ws;
  ushort_t* Abf  = (ushort_t*)p; p += (size_t)4096 * 2048 * 2;    // 16.78 MB
  ushort_t* Xbf  = (ushort_t*)p; p += (size_t)4224 * 2048 * 2;    // 17.30 MB
  ushort_t* Y1   = (ushort_t*)p; p += (size_t)4224 * 4096 * 2;    // 34.60 MB
  ushort_t* Ht   = (ushort_t*)p; p += (size_t)MROWS * KP * 2;     // 92.27 MB
  ushort_t* Ubuf = (ushort_t*)p; p += (size_t)64 * 64 * 2048 * 2; // 16.78 MB
  ushort_t* Wtru = (ushort_t*)p; p += (size_t)128 * KP * 2;       // 90 KB
  ushort_t* Wtc  = (ushort_t*)p; p += (size_t)128 * KP * 2;       // 90 KB

  k_cast<<<1024, 256, 0, stream>>>(s0, Abf, 4194304);
  k_cast<<<1024, 256, 0, stream>>>(s1, Abf + 4194304, 4194304);
  k_build_X<<<4224, 256, 0, stream>>>(inputs, hx, Xbf);
  k_pack_W<<<128, 256, 0, stream>>>(W_ru, 128, Wtru);
  k_pack_W<<<128, 256, 0, stream>>>(W_c, 64, Wtc);

  dim3 g(33, 32);
  dim3 gt(16, 64);
  // conv 1
  k_trans_slot0<<<gt, 256, 0, stream>>>(Xbf, Ht);
  gemm_bt<0><<<g, 256, 0, stream>>>(Xbf, 2048, Abf, nullptr, Y1, Ht);
  gemm_bt<1><<<g, 256, 0, stream>>>(Y1, 4096, Abf, Xbf, nullptr, Ht);
  proj_mfma<0><<<1024, 256, 0, stream>>>(Ht, Wtru, b_ru, hx, Xbf, Ubuf, nullptr);
  // conv 2
  k_trans_slot0<<<gt, 256, 0, stream>>>(Xbf, Ht);
  gemm_bt<0><<<g, 256, 0, stream>>>(Xbf, 2048, Abf, nullptr, Y1, Ht);
  gemm_bt<1><<<g, 256, 0, stream>>>(Y1, 4096, Abf, Xbf, nullptr, Ht);
  proj_mfma<1><<<1024, 256, 0, stream>>>(Ht, Wtc, b_c, hx, nullptr, Ubuf, out);
}